// Round 2
// baseline (35723.834 us; speedup 1.0000x reference)
//
#include <hip/hip_runtime.h>
#include <hip/hip_bf16.h>

// DEQ-GRU: z0 = GRU_x(x); Anderson solve of f(z)=tanh(GRU_z(z)+z0); final f-step; out = z@Wout^T+bout.
// B=64,T=128,D=64,H=256, 3H=768, dL=32768, M_AND=6, THRESHOLD=50, LAM=1e-4, EPS=1e-3, BETA=1.
// Design: bf16 MFMA everywhere; recurrence = 4 persistent WGs (16 batch rows each, full hidden),
// weights register-resident, one __syncthreads per timestep, no cross-WG sync inside an f-eval.

#define DEVFN __device__ __forceinline__

typedef __attribute__((ext_vector_type(8))) short bf16x8_t;
typedef __attribute__((ext_vector_type(4))) float f32x4_t;

DEVFN unsigned short f2bf(float f){
  union { float f; unsigned u; } v; v.f = f;
  unsigned r = v.u + 0x7fffu + ((v.u >> 16) & 1u);
  return (unsigned short)(r >> 16);
}
DEVFN float bf2f(unsigned short h){
  union { unsigned u; float f; } v; v.u = ((unsigned)h) << 16; return v.f;
}
DEVFN float bfhalf(unsigned dw, int hi){
  union { unsigned u; float f; } v; v.u = hi ? (dw & 0xffff0000u) : (dw << 16); return v.f;
}
DEVFN float fexp2f_(float x){ return __builtin_amdgcn_exp2f(x); }
DEVFN float frcp_(float x){ return __builtin_amdgcn_rcpf(x); }
DEVFN float sigm(float x){ return frcp_(1.f + fexp2f_(-1.4426950408889634f * x)); }
DEVFN float tanh_fast(float x){ return 1.f - 2.f * frcp_(1.f + fexp2f_(2.8853900817779268f * x)); }

// ---------------- prep kernels ----------------

__global__ void bias_comb_k(const float* __restrict__ bih, const float* __restrict__ bhh,
                            float* __restrict__ outb){
  int i = blockIdx.x*256 + threadIdx.x;
  if (i < 768) outb[i] = bih[i] + (i < 512 ? bhh[i] : 0.f);
}

__global__ void cvt_bf16_k(const float* __restrict__ in, unsigned short* __restrict__ outp, int nel){
  int i = blockIdx.x*256 + threadIdx.x;
  if (i < nel) outp[i] = f2bf(in[i]);
}

// W [768][K] fp32 -> B-fragment-ordered bf16: out[((nt*KT+kt)*64+lane)*8+i] = W[nt*16+(l&15)][kt*32+(l>>4)*8+i]
__global__ void prep_bfrag_k(const float* __restrict__ W, unsigned short* __restrict__ outp, int KT){
  int idx = blockIdx.x*256 + threadIdx.x;
  int total = 48*KT*64;
  if (idx >= total) return;
  int lane = idx & 63;
  int ktn = idx >> 6;
  int kt = ktn % KT, nt = ktn / KT;
  int K = KT*32;
  int n  = nt*16 + (lane & 15);
  int k0 = kt*32 + (lane >> 4)*8;
  unsigned ow[4];
  #pragma unroll
  for (int i2 = 0; i2 < 4; i2++){
    unsigned lo = f2bf(W[(size_t)n*K + k0 + 2*i2]);
    unsigned hi = f2bf(W[(size_t)n*K + k0 + 2*i2 + 1]);
    ow[i2] = lo | (hi << 16);
  }
  uint4 st; st.x = ow[0]; st.y = ow[1]; st.z = ow[2]; st.w = ow[3];
  *reinterpret_cast<uint4*>(outp + (size_t)idx*8) = st;
}

__global__ void init_sc_k(float* lowest, int* stopped, int* cflag){
  *lowest = 1e8f; *stopped = 0; *cflag = 0;
}

// permute z0 [b][t][j] bf16 -> per-lane 16B chunks matching recurrent gate-math layout
__global__ void permz0_k(const unsigned short* __restrict__ z0, unsigned short* __restrict__ z0p){
  int idx = blockIdx.x*256 + threadIdx.x;         // 4*128*8*64 = 262144
  int l = idx & 63, w = (idx >> 6) & 7, t = (idx >> 9) & 127, grp = idx >> 16;
  unsigned short v[8];
  #pragma unroll
  for (int tt = 0; tt < 2; tt++)
    #pragma unroll
    for (int r = 0; r < 4; r++){
      int b = 16*grp + 4*(l >> 4) + r;
      int j = 32*w + 16*tt + (l & 15);
      v[tt*4 + r] = z0[((size_t)b*128 + t)*256 + j];
    }
  unsigned ow[4];
  #pragma unroll
  for (int i2 = 0; i2 < 4; i2++) ow[i2] = (unsigned)v[2*i2] | ((unsigned)v[2*i2+1] << 16);
  uint4 st; st.x = ow[0]; st.y = ow[1]; st.z = ow[2]; st.w = ow[3];
  *reinterpret_cast<uint4*>(z0p + (size_t)idx*8) = st;
}

// ---------------- input-projection GEMM ----------------
// A[8192][K] bf16 row-major, Bf frag-ordered, bias combined [768]; writes permuted Gi dwords.
__launch_bounds__(256, 4)
__global__ void gemm_k(const unsigned short* __restrict__ A,
                       const unsigned short* __restrict__ Bf,
                       const float* __restrict__ bias,
                       unsigned* __restrict__ Gi,
                       int KT)
{
  const int K = KT*32;
  const int mb = blockIdx.x;        // 0..127, 64 rows each
  const int nb = blockIdx.y;        // 0..7, 96 cols each
  const int tid = threadIdx.x, l = tid & 63, w = tid >> 6;
  const int l15 = l & 15, l4 = l >> 4;
  __shared__ unsigned short As[64*256];           // up to 32KB, XOR-swizzled 16B chunks

  const int cpr = K >> 3;                         // 16B chunks per row
  for (int c = tid; c < 64*cpr; c += 256){
    int row = c / cpr, ch = c % cpr;
    uint4 v = *reinterpret_cast<const uint4*>(A + ((size_t)(mb*64 + row))*K + ch*8);
    int pch = ch ^ (row & 7);
    *reinterpret_cast<uint4*>(&As[row*K + pch*8]) = v;
  }
  __syncthreads();

  f32x4_t acc[6];
  #pragma unroll
  for (int j = 0; j < 6; j++){
    float bv = bias[nb*96 + j*16 + l15];
    acc[j] = (f32x4_t){bv, bv, bv, bv};
  }
  const int arow = 16*w + l15;
  for (int kt = 0; kt < KT; kt++){
    int ch = (kt*4 + l4) ^ (arow & 7);
    bf16x8_t af = *reinterpret_cast<const bf16x8_t*>(&As[arow*K + ch*8]);
    #pragma unroll
    for (int j = 0; j < 6; j++){
      bf16x8_t bb = *reinterpret_cast<const bf16x8_t*>(Bf + (((size_t)((nb*6 + j)*KT + kt))*64 + l)*8);
      acc[j] = __builtin_amdgcn_mfma_f32_16x16x32_bf16(af, bb, acc[j], 0, 0, 0);
    }
  }
  // epilogue -> permuted Gi: dword idx = ((((grp*128+t)*8+wq)*3+gate)*4+rq)*64+lq ; low16 = tt0, high16 = tt1
  const int bidx = mb >> 1;
  const int grp = bidx >> 4, rq = bidx & 3, lq = ((bidx >> 2) & 3)*16 + l15;
  #pragma unroll
  for (int p = 0; p < 3; p++){
    int nb32 = 3*nb + p;
    int wq = nb32 & 7, gate = nb32 >> 3;
    #pragma unroll
    for (int r = 0; r < 4; r++){
      int t = (mb & 1)*64 + 16*w + 4*l4 + r;
      unsigned lo = f2bf(acc[2*p][r]);
      unsigned hi = f2bf(acc[2*p + 1][r]);
      size_t di = ((((size_t)(grp*128 + t)*8 + wq)*3 + gate)*4 + rq)*64 + lq;
      Gi[di] = lo | (hi << 16);
    }
  }
}

// ---------------- sequential GRU recurrence ----------------
// 4 WGs x 512 thr. WG g owns b in [16g,16g+16). Wave w owns hidden j in [32w,32w+32) (all 3 gates).
// mode 0: out = h (GRU_x). mode 1: out = tanh(h + z0).
__launch_bounds__(512, 2)
__global__ void recurrent_k(const unsigned* __restrict__ Gi,
                            const unsigned short* __restrict__ Wfrag,
                            const float* __restrict__ bhh,
                            const unsigned short* __restrict__ z0p,
                            const unsigned short* __restrict__ Xn,
                            unsigned short* __restrict__ fo,
                            unsigned short* __restrict__ fo2,
                            float* __restrict__ diff_part,
                            int mode)
{
  const int g = blockIdx.x;
  const int tid = threadIdx.x;
  const int l = tid & 63, w = tid >> 6;
  const int l15 = l & 15, l4 = l >> 4;

  __shared__ unsigned short hbuf[2][8*64*8];     // 2 x 8KB A-fragment-ordered h (bf16)
  __shared__ unsigned short wlds[8*5*64*8];      // 40KB: kt=7 frags, nt 0..4 per wave
  __shared__ float redp[8];

  const int ntl[6] = {2*w, 2*w + 1, 16 + 2*w, 17 + 2*w, 32 + 2*w, 33 + 2*w};

  bf16x8_t wf[6][7];
  #pragma unroll
  for (int i = 0; i < 6; i++)
    #pragma unroll
    for (int kt = 0; kt < 7; kt++)
      wf[i][kt] = *reinterpret_cast<const bf16x8_t*>(Wfrag + (((size_t)(ntl[i]*8 + kt))*64 + l)*8);
  #pragma unroll
  for (int i = 0; i < 5; i++){
    bf16x8_t v = *reinterpret_cast<const bf16x8_t*>(Wfrag + (((size_t)(ntl[i]*8 + 7))*64 + l)*8);
    *reinterpret_cast<bf16x8_t*>(&wlds[((w*5 + i)*64 + l)*8]) = v;
  }
  bf16x8_t wf57 = *reinterpret_cast<const bf16x8_t*>(Wfrag + (((size_t)(ntl[5]*8 + 7))*64 + l)*8);

  const float bn0 = bhh[ntl[4]*16 + l15];        // n-gate recurrent bias (inside r*(...))
  const float bn1 = bhh[ntl[5]*16 + l15];

  { uint4 z = {0,0,0,0}; *reinterpret_cast<uint4*>(&hbuf[0][tid*8]) = z; }
  float hold[2][4];
  #pragma unroll
  for (int tt = 0; tt < 2; tt++)
    #pragma unroll
    for (int r = 0; r < 4; r++) hold[tt][r] = 0.f;

  float dacc = 0.f;
  int pb = 0;
  __syncthreads();

  for (int t = 0; t < 128; t++){
    const size_t stepm = (size_t)(g*128 + t);
    f32x4_t acc[6];
    #pragma unroll
    for (int i = 0; i < 4; i++) acc[i] = (f32x4_t){0.f, 0.f, 0.f, 0.f};
    acc[4] = (f32x4_t){bn0, bn0, bn0, bn0};
    acc[5] = (f32x4_t){bn1, bn1, bn1, bn1};

    #pragma unroll
    for (int kt = 0; kt < 8; kt++){
      bf16x8_t af = *reinterpret_cast<const bf16x8_t*>(&hbuf[pb][(kt*64 + l)*8]);
      if (kt < 7){
        #pragma unroll
        for (int i = 0; i < 6; i++)
          acc[i] = __builtin_amdgcn_mfma_f32_16x16x32_bf16(af, wf[i][kt], acc[i], 0, 0, 0);
      } else {
        #pragma unroll
        for (int i = 0; i < 5; i++){
          bf16x8_t bb = *reinterpret_cast<const bf16x8_t*>(&wlds[((w*5 + i)*64 + l)*8]);
          acc[i] = __builtin_amdgcn_mfma_f32_16x16x32_bf16(af, bb, acc[i], 0, 0, 0);
        }
        acc[5] = __builtin_amdgcn_mfma_f32_16x16x32_bf16(af, wf57, acc[5], 0, 0, 0);
      }
    }

    const size_t gibase = stepm*6144 + (size_t)w*768 + l;
    uint4 zv = {0,0,0,0};
    if (mode) zv = *reinterpret_cast<const uint4*>(z0p + stepm*4096 + (size_t)w*512 + (size_t)l*8);

    #pragma unroll
    for (int r = 0; r < 4; r++){
      unsigned gr = Gi[gibase + 0*256 + r*64];
      unsigned gz = Gi[gibase + 1*256 + r*64];
      unsigned gn = Gi[gibase + 2*256 + r*64];
      const int b = 16*g + 4*l4 + r;
      const size_t orow = ((size_t)b*128 + t)*256;
      #pragma unroll
      for (int tt = 0; tt < 2; tt++){
        float hr = (tt == 0 ? acc[0] : acc[1])[r];
        float hz = (tt == 0 ? acc[2] : acc[3])[r];
        float hn = (tt == 0 ? acc[4] : acc[5])[r];
        float rg = sigm(bfhalf(gr, tt) + hr);
        float zg = sigm(bfhalf(gz, tt) + hz);
        float nn = tanh_fast(bfhalf(gn, tt) + rg*hn);
        float h = nn + zg*(hold[tt][r] - nn);
        hold[tt][r] = h;
        int kgrp = 2*tt + (l15 >> 3);
        int lane2 = (4*l4 + r) + 16*kgrp;
        hbuf[pb ^ 1][(w*64 + lane2)*8 + (l15 & 7)] = f2bf(h);
        int j = 32*w + 16*tt + l15;
        float ov;
        if (mode){
          int q = tt*4 + r;
          unsigned zw = ((q >> 1) == 0) ? zv.x : ((q >> 1) == 1) ? zv.y : ((q >> 1) == 2) ? zv.z : zv.w;
          ov = tanh_fast(h + bfhalf(zw, q & 1));
        } else {
          ov = h;
        }
        unsigned short ob = f2bf(ov);
        fo[orow + j] = ob;
        if (fo2) fo2[orow + j] = ob;
        if (Xn){ float d = ov - bf2f(Xn[orow + j]); dacc += d*d; }
      }
    }
    __syncthreads();
    pb ^= 1;
  }

  #pragma unroll
  for (int off = 32; off > 0; off >>= 1) dacc += __shfl_down(dacc, off);
  if (l == 0) redp[w] = dacc;
  __syncthreads();
  if (tid == 0){
    float s = 0.f;
    #pragma unroll
    for (int i = 0; i < 8; i++) s += redp[i];
    diff_part[g] = s;
  }
}

// ---------------- Anderson machinery ----------------

__global__ void anderson_pre_k(const unsigned short* __restrict__ X,
                               const unsigned short* __restrict__ F,
                               float* __restrict__ GGT)
{
  const int b = blockIdx.x, tid = threadIdx.x;
  const int l = tid & 63, w = tid >> 6;
  __shared__ float redp[4*21];
  const size_t SL = (size_t)64*32768;
  const size_t base = (size_t)b*32768;
  float p[21];
  #pragma unroll
  for (int q = 0; q < 21; q++) p[q] = 0.f;
  for (int d0 = tid*8; d0 < 32768; d0 += 2048){
    float gv[6][8];
    #pragma unroll
    for (int s = 0; s < 6; s++){
      uint4 fv = *reinterpret_cast<const uint4*>(F + s*SL + base + d0);
      uint4 xv = *reinterpret_cast<const uint4*>(X + s*SL + base + d0);
      unsigned fw[4] = {fv.x, fv.y, fv.z, fv.w};
      unsigned xw[4] = {xv.x, xv.y, xv.z, xv.w};
      #pragma unroll
      for (int e = 0; e < 8; e++) gv[s][e] = bfhalf(fw[e >> 1], e & 1) - bfhalf(xw[e >> 1], e & 1);
    }
    int q = 0;
    #pragma unroll
    for (int i = 0; i < 6; i++)
      #pragma unroll
      for (int jj = i; jj < 6; jj++){
        float s2 = 0.f;
        #pragma unroll
        for (int e = 0; e < 8; e++) s2 += gv[i][e]*gv[jj][e];
        p[q++] += s2;
      }
  }
  #pragma unroll
  for (int q = 0; q < 21; q++){
    float v = p[q];
    #pragma unroll
    for (int off = 32; off > 0; off >>= 1) v += __shfl_down(v, off);
    if (l == 0) redp[w*21 + q] = v;
  }
  __syncthreads();
  if (tid < 21){
    const int PI[21] = {0,0,0,0,0,0, 1,1,1,1,1, 2,2,2,2, 3,3,3, 4,4, 5};
    const int PJ[21] = {0,1,2,3,4,5, 1,2,3,4,5, 2,3,4,5, 3,4,5, 4,5, 5};
    float s = redp[tid] + redp[21 + tid] + redp[42 + tid] + redp[63 + tid];
    GGT[b*36 + PI[tid]*6 + PJ[tid]] = s;
    GGT[b*36 + PJ[tid]*6 + PI[tid]] = s;
  }
}

__global__ void anderson_solve_k(const float* __restrict__ GGT, float* __restrict__ alpha, int n){
  int b = threadIdx.x;
  if (b >= 64) return;
  int m = n + 1;
  float A[7][8];
  for (int i = 0; i < 7; i++)
    for (int j = 0; j < 8; j++) A[i][j] = 0.f;
  for (int j = 1; j < m; j++) A[0][j] = 1.f;
  for (int i = 1; i < m; i++){
    A[i][0] = 1.f;
    for (int j = 1; j < m; j++)
      A[i][j] = GGT[b*36 + (i-1)*6 + (j-1)] + ((i == j) ? 1e-4f : 0.f);
  }
  A[0][7] = 1.f;                                  // rhs = e0
  for (int c = 0; c < m; c++){
    int piv = c; float mx = fabsf(A[c][c]);
    for (int i = c + 1; i < m; i++){
      float v = fabsf(A[i][c]);
      if (v > mx){ mx = v; piv = i; }
    }
    if (piv != c)
      for (int j = 0; j < 8; j++){ float tsw = A[c][j]; A[c][j] = A[piv][j]; A[piv][j] = tsw; }
    float inv = 1.f / A[c][c];
    for (int j = c; j < 8; j++) A[c][j] *= inv;
    for (int i = 0; i < m; i++) if (i != c){
      float f = A[i][c];
      for (int j = c; j < 8; j++) A[i][j] -= f*A[c][j];
    }
  }
  for (int s = 0; s < 6; s++) alpha[b*6 + s] = (s + 1 < m) ? A[s+1][7] : 0.f;
}

__global__ void xnew_k(const unsigned short* __restrict__ F, const float* __restrict__ al,
                       unsigned short* __restrict__ Xd)
{
  const size_t SL = (size_t)64*32768;
  size_t idx = (size_t)blockIdx.x*256 + threadIdx.x;   // 262144
  size_t e0 = idx*8;
  int b = (int)(e0 >> 15);
  float a[6];
  #pragma unroll
  for (int s = 0; s < 6; s++) a[s] = al[b*6 + s];
  float o[8];
  #pragma unroll
  for (int e = 0; e < 8; e++) o[e] = 0.f;
  #pragma unroll
  for (int s = 0; s < 6; s++){
    uint4 fv = *reinterpret_cast<const uint4*>(F + s*SL + e0);
    unsigned fw[4] = {fv.x, fv.y, fv.z, fv.w};
    #pragma unroll
    for (int e = 0; e < 8; e++) o[e] += a[s]*bfhalf(fw[e >> 1], e & 1);
  }
  unsigned ow[4];
  #pragma unroll
  for (int i2 = 0; i2 < 4; i2++){
    unsigned lo = f2bf(o[2*i2]), hi = f2bf(o[2*i2 + 1]);
    ow[i2] = lo | (hi << 16);
  }
  uint4 st; st.x = ow[0]; st.y = ow[1]; st.z = ow[2]; st.w = ow[3];
  *reinterpret_cast<uint4*>(Xd + e0) = st;
}

__global__ void anderson_post_k(const float* __restrict__ dp, float* lowest, int* stopped, int* cflag){
  float d = sqrtf(dp[0] + dp[1] + dp[2] + dp[3]);
  int act = (*stopped == 0);
  int imp = act && (d < *lowest);
  *cflag = imp;
  if (imp) *lowest = d;
  if (act && (d < 1e-3f)) *stopped = 1;
}

__global__ void cond_copy_k(const uint4* __restrict__ s, uint4* __restrict__ d, const int* __restrict__ flag){
  if (*flag == 0) return;
  size_t i = (size_t)blockIdx.x*256 + threadIdx.x;
  d[i] = s[i];
}

__global__ void outproj_k(const unsigned short* __restrict__ z, const float* __restrict__ Wout,
                          const float* __restrict__ bout, float* __restrict__ outp){
  const int b = blockIdx.x, tid = threadIdx.x, l = tid & 63, w = tid >> 6;
  __shared__ float redp[4];
  float s = 0.f;
  for (int d = tid*8; d < 32768; d += 2048){
    uint4 zv = *reinterpret_cast<const uint4*>(z + (size_t)b*32768 + d);
    unsigned zw[4] = {zv.x, zv.y, zv.z, zv.w};
    float4 w0 = *reinterpret_cast<const float4*>(Wout + d);
    float4 w1 = *reinterpret_cast<const float4*>(Wout + d + 4);
    s += bfhalf(zw[0],0)*w0.x + bfhalf(zw[0],1)*w0.y + bfhalf(zw[1],0)*w0.z + bfhalf(zw[1],1)*w0.w
       + bfhalf(zw[2],0)*w1.x + bfhalf(zw[2],1)*w1.y + bfhalf(zw[3],0)*w1.z + bfhalf(zw[3],1)*w1.w;
  }
  #pragma unroll
  for (int off = 32; off > 0; off >>= 1) s += __shfl_down(s, off);
  if (l == 0) redp[w] = s;
  __syncthreads();
  if (tid == 0) outp[b] = redp[0] + redp[1] + redp[2] + redp[3] + bout[0];
}

// ---------------- host orchestration ----------------

extern "C" void kernel_launch(void* const* d_in, const int* in_sizes, int n_in,
                              void* d_out, int out_size, void* d_ws, size_t ws_size,
                              hipStream_t stream)
{
  const float* x     = (const float*)d_in[0];
  const float* Wih_x = (const float*)d_in[1];
  const float* Whh_x = (const float*)d_in[2];
  const float* bih_x = (const float*)d_in[3];
  const float* bhh_x = (const float*)d_in[4];
  const float* Wih_z = (const float*)d_in[5];
  const float* Whh_z = (const float*)d_in[6];
  const float* bih_z = (const float*)d_in[7];
  const float* bhh_z = (const float*)d_in[8];
  const float* Wout  = (const float*)d_in[9];
  const float* bout  = (const float*)d_in[10];
  float* outp = (float*)d_out;
  (void)in_sizes; (void)n_in; (void)out_size; (void)ws_size;

  char* basep = (char*)d_ws;
  size_t off = 0;
  auto alloc = [&](size_t bytes)->char*{
    char* r = basep + off; off = (off + bytes + 255) & ~(size_t)255; return r;
  };
  const size_t EL = (size_t)64*128*256;            // 2,097,152 elems per state tensor

  unsigned short* z0b  = (unsigned short*)alloc(EL*2);
  unsigned short* z0p  = (unsigned short*)alloc(EL*2);
  unsigned short* Xs   = (unsigned short*)alloc(EL*2*6);
  unsigned short* Fs   = (unsigned short*)alloc(EL*2*6);
  unsigned short* lowb = (unsigned short*)alloc(EL*2);
  unsigned short* zfin = (unsigned short*)alloc(EL*2);
  unsigned short* xbf  = (unsigned short*)alloc((size_t)64*128*64*2);
  unsigned*       Gi   = (unsigned*)alloc((size_t)64*128*768*2);  // 3,145,728 dwords = 12.58MB
  unsigned short* fIx  = (unsigned short*)alloc((size_t)48*2*64*8*2);
  unsigned short* fHx  = (unsigned short*)alloc((size_t)48*8*64*8*2);
  unsigned short* fIz  = (unsigned short*)alloc((size_t)48*8*64*8*2);
  unsigned short* fHz  = (unsigned short*)alloc((size_t)48*8*64*8*2);
  float* biasX  = (float*)alloc(768*4);
  float* biasZ  = (float*)alloc(768*4);
  float* GGT    = (float*)alloc(64*36*4);
  float* alph   = (float*)alloc(64*6*4);
  float* dpart  = (float*)alloc(4*4);
  float* lowest = (float*)alloc(4);
  int*   stopped= (int*)alloc(4);
  int*   cflag  = (int*)alloc(4);

  // prep
  bias_comb_k<<<3,256,0,stream>>>(bih_x, bhh_x, biasX);
  bias_comb_k<<<3,256,0,stream>>>(bih_z, bhh_z, biasZ);
  cvt_bf16_k<<<2048,256,0,stream>>>(x, xbf, 64*128*64);
  prep_bfrag_k<<<24,256,0,stream>>>(Wih_x, fIx, 2);
  prep_bfrag_k<<<96,256,0,stream>>>(Whh_x, fHx, 8);
  prep_bfrag_k<<<96,256,0,stream>>>(Wih_z, fIz, 8);
  prep_bfrag_k<<<96,256,0,stream>>>(Whh_z, fHz, 8);
  init_sc_k<<<1,1,0,stream>>>(lowest, stopped, cflag);

  dim3 gg(128, 8);
  // z0 = GRU_x(x); X[0] = x0 = z0
  gemm_k<<<gg,256,0,stream>>>(xbf, fIx, biasX, Gi, 2);
  recurrent_k<<<4,512,0,stream>>>(Gi, fHx, bhh_x, nullptr, nullptr, z0b, Xs, dpart, 0);
  permz0_k<<<1024,256,0,stream>>>(z0b, z0p);
  hipMemcpyAsync(lowb, z0b, EL*2, hipMemcpyDeviceToDevice, stream);   // lowest_xest init = x0
  // F[0] = f(x0); X[1] = F[0]
  gemm_k<<<gg,256,0,stream>>>(z0b, fIz, biasZ, Gi, 8);
  recurrent_k<<<4,512,0,stream>>>(Gi, fHz, bhh_z, z0p, nullptr, Fs, Xs + EL, dpart, 1);
  // F[1] = f(F[0])
  gemm_k<<<gg,256,0,stream>>>(Xs + EL, fIz, biasZ, Gi, 8);
  recurrent_k<<<4,512,0,stream>>>(Gi, fHz, bhh_z, z0p, nullptr, Fs + EL, nullptr, dpart, 1);

  for (int k = 2; k < 50; k++){
    int s = k % 6;
    int n = (k < 6) ? k : 6;
    anderson_pre_k<<<64,256,0,stream>>>(Xs, Fs, GGT);
    anderson_solve_k<<<1,64,0,stream>>>(GGT, alph, n);
    xnew_k<<<1024,256,0,stream>>>(Fs, alph, Xs + (size_t)s*EL);
    gemm_k<<<gg,256,0,stream>>>(Xs + (size_t)s*EL, fIz, biasZ, Gi, 8);
    recurrent_k<<<4,512,0,stream>>>(Gi, fHz, bhh_z, z0p, Xs + (size_t)s*EL, Fs + (size_t)s*EL, nullptr, dpart, 1);
    anderson_post_k<<<1,1,0,stream>>>(dpart, lowest, stopped, cflag);
    cond_copy_k<<<1024,256,0,stream>>>((const uint4*)(Xs + (size_t)s*EL), (uint4*)lowb, cflag);
  }

  // final differentiable step + output projection
  gemm_k<<<gg,256,0,stream>>>(lowb, fIz, biasZ, Gi, 8);
  recurrent_k<<<4,512,0,stream>>>(Gi, fHz, bhh_z, z0p, nullptr, zfin, nullptr, dpart, 1);
  outproj_k<<<64,256,0,stream>>>(zfin, Wout, bout, outp);
}

// Round 4
// 15269.145 us; speedup vs baseline: 2.3396x; 2.3396x over previous
//
#include <hip/hip_runtime.h>
#include <hip/hip_bf16.h>

// DEQ-GRU: z0 = GRU_x(x); Anderson solve of f(z)=tanh(GRU_z(z)+z0); final f-step; out = z@Wout^T+bout.
// B=64,T=128,D=64,H=256, 3H=768, dL=32768, M_AND=6, THRESHOLD=50, LAM=1e-4, EPS=1e-3, BETA=1.
// R3: recurrent_k slimmed to pure recurrence (gates only, one uint4 store/step, raw barrier with
// lgkmcnt-only drain, Gi prefetched at top of step); tanh/z0-add/diff deferred to parallel act_k.

#define DEVFN __device__ __forceinline__

typedef __attribute__((ext_vector_type(8))) short bf16x8_t;
typedef __attribute__((ext_vector_type(4))) float f32x4_t;

DEVFN unsigned short f2bf(float f){
  union { float f; unsigned u; } v; v.f = f;
  unsigned r = v.u + 0x7fffu + ((v.u >> 16) & 1u);
  return (unsigned short)(r >> 16);
}
DEVFN float bf2f(unsigned short h){
  union { unsigned u; float f; } v; v.u = ((unsigned)h) << 16; return v.f;
}
DEVFN float bfhalf(unsigned dw, int hi){
  union { unsigned u; float f; } v; v.u = hi ? (dw & 0xffff0000u) : (dw << 16); return v.f;
}
DEVFN float fexp2f_(float x){ return __builtin_amdgcn_exp2f(x); }
DEVFN float frcp_(float x){ return __builtin_amdgcn_rcpf(x); }
DEVFN float sigm(float x){ return frcp_(1.f + fexp2f_(-1.4426950408889634f * x)); }
DEVFN float tanh_fast(float x){ return 1.f - 2.f * frcp_(1.f + fexp2f_(2.8853900817779268f * x)); }

struct P6 { const unsigned short* p[6]; };

// ---------------- prep kernels ----------------

__global__ void bias_comb_k(const float* __restrict__ bih, const float* __restrict__ bhh,
                            float* __restrict__ outb){
  int i = blockIdx.x*256 + threadIdx.x;
  if (i < 768) outb[i] = bih[i] + (i < 512 ? bhh[i] : 0.f);
}

__global__ void cvt_bf16_k(const float* __restrict__ in, unsigned short* __restrict__ outp, int nel){
  int i = blockIdx.x*256 + threadIdx.x;
  if (i < nel) outp[i] = f2bf(in[i]);
}

// W [768][K] fp32 -> B-fragment-ordered bf16: out[((nt*KT+kt)*64+lane)*8+i] = W[nt*16+(l&15)][kt*32+(l>>4)*8+i]
__global__ void prep_bfrag_k(const float* __restrict__ W, unsigned short* __restrict__ outp, int KT){
  int idx = blockIdx.x*256 + threadIdx.x;
  int total = 48*KT*64;
  if (idx >= total) return;
  int lane = idx & 63;
  int ktn = idx >> 6;
  int kt = ktn % KT, nt = ktn / KT;
  int K = KT*32;
  int n  = nt*16 + (lane & 15);
  int k0 = kt*32 + (lane >> 4)*8;
  unsigned ow[4];
  #pragma unroll
  for (int i2 = 0; i2 < 4; i2++){
    unsigned lo = f2bf(W[(size_t)n*K + k0 + 2*i2]);
    unsigned hi = f2bf(W[(size_t)n*K + k0 + 2*i2 + 1]);
    ow[i2] = lo | (hi << 16);
  }
  uint4 st; st.x = ow[0]; st.y = ow[1]; st.z = ow[2]; st.w = ow[3];
  *reinterpret_cast<uint4*>(outp + (size_t)idx*8) = st;
}

__global__ void init_sc_k(float* lowest, int* stopped, int* cflag){
  *lowest = 1e8f; *stopped = 0; *cflag = 0;
}

// ---------------- input-projection GEMM ----------------
__launch_bounds__(256, 4)
__global__ void gemm_k(const unsigned short* __restrict__ A,
                       const unsigned short* __restrict__ Bf,
                       const float* __restrict__ bias,
                       unsigned* __restrict__ Gi,
                       int KT)
{
  const int K = KT*32;
  const int mb = blockIdx.x;        // 0..127, 64 rows each
  const int nb = blockIdx.y;        // 0..7, 96 cols each
  const int tid = threadIdx.x, l = tid & 63, w = tid >> 6;
  const int l15 = l & 15, l4 = l >> 4;
  __shared__ unsigned short As[64*256];           // up to 32KB, XOR-swizzled 16B chunks

  const int cpr = K >> 3;                         // 16B chunks per row
  for (int c = tid; c < 64*cpr; c += 256){
    int row = c / cpr, ch = c % cpr;
    uint4 v = *reinterpret_cast<const uint4*>(A + ((size_t)(mb*64 + row))*K + ch*8);
    int pch = ch ^ (row & 7);
    *reinterpret_cast<uint4*>(&As[row*K + pch*8]) = v;
  }
  __syncthreads();

  f32x4_t acc[6];
  #pragma unroll
  for (int j = 0; j < 6; j++){
    float bv = bias[nb*96 + j*16 + l15];
    acc[j] = (f32x4_t){bv, bv, bv, bv};
  }
  const int arow = 16*w + l15;
  for (int kt = 0; kt < KT; kt++){
    int ch = (kt*4 + l4) ^ (arow & 7);
    bf16x8_t af = *reinterpret_cast<const bf16x8_t*>(&As[arow*K + ch*8]);
    #pragma unroll
    for (int j = 0; j < 6; j++){
      bf16x8_t bb = *reinterpret_cast<const bf16x8_t*>(Bf + (((size_t)((nb*6 + j)*KT + kt))*64 + l)*8);
      acc[j] = __builtin_amdgcn_mfma_f32_16x16x32_bf16(af, bb, acc[j], 0, 0, 0);
    }
  }
  // epilogue -> permuted Gi: dword idx = ((((grp*128+t)*8+wq)*3+gate)*4+rq)*64+lq ; low16 = tt0, high16 = tt1
  const int bidx = mb >> 1;
  const int grp = bidx >> 4, rq = bidx & 3, lq = ((bidx >> 2) & 3)*16 + l15;
  #pragma unroll
  for (int p = 0; p < 3; p++){
    int nb32 = 3*nb + p;
    int wq = nb32 & 7, gate = nb32 >> 3;
    #pragma unroll
    for (int r = 0; r < 4; r++){
      int t = (mb & 1)*64 + 16*w + 4*l4 + r;
      unsigned lo = f2bf(acc[2*p][r]);
      unsigned hi = f2bf(acc[2*p + 1][r]);
      size_t di = ((((size_t)(grp*128 + t)*8 + wq)*3 + gate)*4 + rq)*64 + lq;
      Gi[di] = lo | (hi << 16);
    }
  }
}

// ---------------- sequential GRU recurrence (gates only) ----------------
// 4 WGs x 512 thr. WG g owns b in [16g,16g+16). Wave w owns hidden j in [32w,32w+32) (all 3 gates).
// Writes ONLY hperm (z0p-layout uint4 per thread per step). No tanh/z0/diff here.
__launch_bounds__(512, 2)
__global__ void recurrent_k(const unsigned* __restrict__ Gi,
                            const unsigned short* __restrict__ Wfrag,
                            const float* __restrict__ bhh,
                            uint4* __restrict__ hperm)
{
  const int g = blockIdx.x;
  const int tid = threadIdx.x;
  const int l = tid & 63, w = tid >> 6;
  const int l15 = l & 15, l4 = l >> 4;

  __shared__ unsigned short hbuf[2][4096];       // 2 x 8KB A-fragment-ordered h (bf16)
  __shared__ unsigned short wlds[8*6*64*8];      // 48KB: kt=7 frags, nt 0..5 per wave

  const int ntl[6] = {2*w, 2*w + 1, 16 + 2*w, 17 + 2*w, 32 + 2*w, 33 + 2*w};

  bf16x8_t wf[6][7];
  #pragma unroll
  for (int i = 0; i < 6; i++)
    #pragma unroll
    for (int kt = 0; kt < 7; kt++)
      wf[i][kt] = *reinterpret_cast<const bf16x8_t*>(Wfrag + (((size_t)(ntl[i]*8 + kt))*64 + l)*8);
  #pragma unroll
  for (int i = 0; i < 6; i++){
    bf16x8_t v = *reinterpret_cast<const bf16x8_t*>(Wfrag + (((size_t)(ntl[i]*8 + 7))*64 + l)*8);
    *reinterpret_cast<bf16x8_t*>(&wlds[((w*6 + i)*64 + l)*8]) = v;
  }

  const float bn0 = bhh[ntl[4]*16 + l15];        // n-gate recurrent bias (inside r*(...))
  const float bn1 = bhh[ntl[5]*16 + l15];

  { uint4 z = {0,0,0,0}; *reinterpret_cast<uint4*>(&hbuf[0][tid*8]) = z; }
  float hold[2][4];
  #pragma unroll
  for (int tt = 0; tt < 2; tt++)
    #pragma unroll
    for (int r = 0; r < 4; r++) hold[tt][r] = 0.f;

  int pb = 0;
  __syncthreads();

  for (int t = 0; t < 128; t++){
    const size_t stepm = (size_t)(g*128 + t);
    // prefetch this step's gate inputs first (independent of hbuf) — hides L2/L3 latency under MFMAs
    const size_t gib = stepm*6144 + (size_t)w*768 + l;
    unsigned gd[3][4];
    #pragma unroll
    for (int gate = 0; gate < 3; gate++)
      #pragma unroll
      for (int r = 0; r < 4; r++)
        gd[gate][r] = Gi[gib + (size_t)gate*256 + r*64];

    f32x4_t acc[6];
    #pragma unroll
    for (int i = 0; i < 4; i++) acc[i] = (f32x4_t){0.f, 0.f, 0.f, 0.f};
    acc[4] = (f32x4_t){bn0, bn0, bn0, bn0};
    acc[5] = (f32x4_t){bn1, bn1, bn1, bn1};

    #pragma unroll
    for (int kt = 0; kt < 8; kt++){
      bf16x8_t af = *reinterpret_cast<const bf16x8_t*>(&hbuf[pb][(kt*64 + l)*8]);
      if (kt < 7){
        #pragma unroll
        for (int i = 0; i < 6; i++)
          acc[i] = __builtin_amdgcn_mfma_f32_16x16x32_bf16(af, wf[i][kt], acc[i], 0, 0, 0);
      } else {
        #pragma unroll
        for (int i = 0; i < 6; i++){
          bf16x8_t bb = *reinterpret_cast<const bf16x8_t*>(&wlds[((w*6 + i)*64 + l)*8]);
          acc[i] = __builtin_amdgcn_mfma_f32_16x16x32_bf16(af, bb, acc[i], 0, 0, 0);
        }
      }
    }

    unsigned short hb[2][4];
    #pragma unroll
    for (int r = 0; r < 4; r++){
      #pragma unroll
      for (int tt = 0; tt < 2; tt++){
        float hr = (tt == 0 ? acc[0] : acc[1])[r];
        float hz = (tt == 0 ? acc[2] : acc[3])[r];
        float hn = (tt == 0 ? acc[4] : acc[5])[r];
        float rg = sigm(bfhalf(gd[0][r], tt) + hr);
        float zg = sigm(bfhalf(gd[1][r], tt) + hz);
        float nn = tanh_fast(bfhalf(gd[2][r], tt) + rg*hn);
        float h = nn + zg*(hold[tt][r] - nn);
        hold[tt][r] = h;
        unsigned short hbv = f2bf(h);
        hb[tt][r] = hbv;
        int kgrp = 2*tt + (l15 >> 3);
        int lane2 = (4*l4 + r) + 16*kgrp;
        hbuf[pb ^ 1][(w*64 + lane2)*8 + (l15 & 7)] = hbv;
      }
    }
    // one coalesced 16B store of this thread's 8 h values (z0p-layout)
    uint4 hp;
    hp.x = (unsigned)hb[0][0] | ((unsigned)hb[0][1] << 16);
    hp.y = (unsigned)hb[0][2] | ((unsigned)hb[0][3] << 16);
    hp.z = (unsigned)hb[1][0] | ((unsigned)hb[1][1] << 16);
    hp.w = (unsigned)hb[1][2] | ((unsigned)hb[1][3] << 16);
    hperm[stepm*512 + (size_t)w*64 + l] = hp;

    // raw barrier: drain LDS writes only; global ops stay in flight
    __builtin_amdgcn_sched_barrier(0);
    asm volatile("s_waitcnt lgkmcnt(0)" ::: "memory");
    __builtin_amdgcn_s_barrier();
    __builtin_amdgcn_sched_barrier(0);
    pb ^= 1;
  }
}

// ---------------- activation / diff kernels (fully parallel) ----------------

// unpermute h -> standard [b][t][j] (GRU_x output z0)
__global__ void act0_k(const uint4* __restrict__ hperm, unsigned short* __restrict__ outstd){
  int idx = blockIdx.x*256 + threadIdx.x;        // 262144
  int l = idx & 63, w = (idx >> 6) & 7, t = (idx >> 9) & 127, grp = idx >> 16;
  uint4 hp = hperm[idx];
  unsigned hw[4] = {hp.x, hp.y, hp.z, hp.w};
  #pragma unroll
  for (int e = 0; e < 8; e++){
    unsigned short v = (e & 1) ? (unsigned short)(hw[e >> 1] >> 16) : (unsigned short)(hw[e >> 1] & 0xffff);
    int b = 16*grp + 4*(l >> 4) + (e & 3);
    int j = 32*w + 16*(e >> 2) + (l & 15);
    outstd[((size_t)b*128 + t)*256 + j] = v;
  }
}

// f-step finish: F = tanh(h + z0), standard layout; optional ||F - X||^2 partials per block
__global__ void act1_k(const uint4* __restrict__ hperm, const uint4* __restrict__ z0p,
                       unsigned short* __restrict__ Fout, const unsigned short* __restrict__ Xn,
                       float* __restrict__ dpart){
  int idx = blockIdx.x*256 + threadIdx.x;        // 262144
  int l = idx & 63, w = (idx >> 6) & 7, t = (idx >> 9) & 127, grp = idx >> 16;
  uint4 hp = hperm[idx];
  uint4 zp = z0p[idx];
  unsigned hw[4] = {hp.x, hp.y, hp.z, hp.w};
  unsigned zw[4] = {zp.x, zp.y, zp.z, zp.w};
  float dacc = 0.f;
  #pragma unroll
  for (int e = 0; e < 8; e++){
    float h  = bfhalf(hw[e >> 1], e & 1);
    float z0 = bfhalf(zw[e >> 1], e & 1);
    float ov = tanh_fast(h + z0);
    int b = 16*grp + 4*(l >> 4) + (e & 3);
    int j = 32*w + 16*(e >> 2) + (l & 15);
    size_t o = ((size_t)b*128 + t)*256 + j;
    Fout[o] = f2bf(ov);
    if (Xn){ float d = ov - bf2f(Xn[o]); dacc += d*d; }
  }
  if (dpart){
    __shared__ float rp[4];
    #pragma unroll
    for (int off = 32; off > 0; off >>= 1) dacc += __shfl_down(dacc, off);
    if ((threadIdx.x & 63) == 0) rp[threadIdx.x >> 6] = dacc;
    __syncthreads();
    if (threadIdx.x == 0) dpart[blockIdx.x] = rp[0] + rp[1] + rp[2] + rp[3];
  }
}

// ---------------- Anderson machinery ----------------

__global__ void anderson_pre_k(P6 X, P6 F, float* __restrict__ GGT)
{
  const int b = blockIdx.x, tid = threadIdx.x;
  const int l = tid & 63, w = tid >> 6;
  __shared__ float redp[4*21];
  const size_t base = (size_t)b*32768;
  float p[21];
  #pragma unroll
  for (int q = 0; q < 21; q++) p[q] = 0.f;
  for (int d0 = tid*8; d0 < 32768; d0 += 2048){
    float gv[6][8];
    #pragma unroll
    for (int s = 0; s < 6; s++){
      uint4 fv = *reinterpret_cast<const uint4*>(F.p[s] + base + d0);
      uint4 xv = *reinterpret_cast<const uint4*>(X.p[s] + base + d0);
      unsigned fw[4] = {fv.x, fv.y, fv.z, fv.w};
      unsigned xw[4] = {xv.x, xv.y, xv.z, xv.w};
      #pragma unroll
      for (int e = 0; e < 8; e++) gv[s][e] = bfhalf(fw[e >> 1], e & 1) - bfhalf(xw[e >> 1], e & 1);
    }
    int q = 0;
    #pragma unroll
    for (int i = 0; i < 6; i++)
      #pragma unroll
      for (int jj = i; jj < 6; jj++){
        float s2 = 0.f;
        #pragma unroll
        for (int e = 0; e < 8; e++) s2 += gv[i][e]*gv[jj][e];
        p[q++] += s2;
      }
  }
  #pragma unroll
  for (int q = 0; q < 21; q++){
    float v = p[q];
    #pragma unroll
    for (int off = 32; off > 0; off >>= 1) v += __shfl_down(v, off);
    if (l == 0) redp[w*21 + q] = v;
  }
  __syncthreads();
  if (tid < 21){
    const int PI[21] = {0,0,0,0,0,0, 1,1,1,1,1, 2,2,2,2, 3,3,3, 4,4, 5};
    const int PJ[21] = {0,1,2,3,4,5, 1,2,3,4,5, 2,3,4,5, 3,4,5, 4,5, 5};
    float s = redp[tid] + redp[21 + tid] + redp[42 + tid] + redp[63 + tid];
    GGT[b*36 + PI[tid]*6 + PJ[tid]] = s;
    GGT[b*36 + PJ[tid]*6 + PI[tid]] = s;
  }
}

__global__ void anderson_solve_k(const float* __restrict__ GGT, float* __restrict__ alpha, int n){
  int b = threadIdx.x;
  if (b >= 64) return;
  int m = n + 1;
  float A[7][8];
  for (int i = 0; i < 7; i++)
    for (int j = 0; j < 8; j++) A[i][j] = 0.f;
  for (int j = 1; j < m; j++) A[0][j] = 1.f;
  for (int i = 1; i < m; i++){
    A[i][0] = 1.f;
    for (int j = 1; j < m; j++)
      A[i][j] = GGT[b*36 + (i-1)*6 + (j-1)] + ((i == j) ? 1e-4f : 0.f);
  }
  A[0][7] = 1.f;                                  // rhs = e0
  for (int c = 0; c < m; c++){
    int piv = c; float mx = fabsf(A[c][c]);
    for (int i = c + 1; i < m; i++){
      float v = fabsf(A[i][c]);
      if (v > mx){ mx = v; piv = i; }
    }
    if (piv != c)
      for (int j = 0; j < 8; j++){ float tsw = A[c][j]; A[c][j] = A[piv][j]; A[piv][j] = tsw; }
    float inv = 1.f / A[c][c];
    for (int j = c; j < 8; j++) A[c][j] *= inv;
    for (int i = 0; i < m; i++) if (i != c){
      float f = A[i][c];
      for (int j = c; j < 8; j++) A[i][j] -= f*A[c][j];
    }
  }
  for (int s = 0; s < 6; s++) alpha[b*6 + s] = (s + 1 < m) ? A[s+1][7] : 0.f;
}

__global__ void xnew_k(P6 F, const float* __restrict__ al, unsigned short* __restrict__ Xd)
{
  size_t idx = (size_t)blockIdx.x*256 + threadIdx.x;   // 262144
  size_t e0 = idx*8;
  int b = (int)(e0 >> 15);
  float a[6];
  #pragma unroll
  for (int s = 0; s < 6; s++) a[s] = al[b*6 + s];
  float o[8];
  #pragma unroll
  for (int e = 0; e < 8; e++) o[e] = 0.f;
  #pragma unroll
  for (int s = 0; s < 6; s++){
    uint4 fv = *reinterpret_cast<const uint4*>(F.p[s] + e0);
    unsigned fw[4] = {fv.x, fv.y, fv.z, fv.w};
    #pragma unroll
    for (int e = 0; e < 8; e++) o[e] += a[s]*bfhalf(fw[e >> 1], e & 1);
  }
  unsigned ow[4];
  #pragma unroll
  for (int i2 = 0; i2 < 4; i2++){
    unsigned lo = f2bf(o[2*i2]), hi = f2bf(o[2*i2 + 1]);
    ow[i2] = lo | (hi << 16);
  }
  uint4 st; st.x = ow[0]; st.y = ow[1]; st.z = ow[2]; st.w = ow[3];
  *reinterpret_cast<uint4*>(Xd + e0) = st;
}

__global__ void anderson_post_k(const float* __restrict__ dp, float* lowest, int* stopped, int* cflag){
  int tid = threadIdx.x;
  float s = 0.f;
  for (int i = tid; i < 1024; i += 256) s += dp[i];
  __shared__ float rp[4];
  #pragma unroll
  for (int off = 32; off > 0; off >>= 1) s += __shfl_down(s, off);
  if ((tid & 63) == 0) rp[tid >> 6] = s;
  __syncthreads();
  if (tid == 0){
    float d = sqrtf(rp[0] + rp[1] + rp[2] + rp[3]);
    int act = (*stopped == 0);
    int imp = act && (d < *lowest);
    *cflag = imp;
    if (imp) *lowest = d;
    if (act && (d < 1e-3f)) *stopped = 1;
  }
}

__global__ void cond_copy_k(const uint4* __restrict__ s, uint4* __restrict__ d, const int* __restrict__ flag){
  if (*flag == 0) return;
  size_t i = (size_t)blockIdx.x*256 + threadIdx.x;
  d[i] = s[i];
}

__global__ void outproj_k(const unsigned short* __restrict__ z, const float* __restrict__ Wout,
                          const float* __restrict__ bout, float* __restrict__ outp){
  const int b = blockIdx.x, tid = threadIdx.x, l = tid & 63, w = tid >> 6;
  __shared__ float redp[4];
  float s = 0.f;
  for (int d = tid*8; d < 32768; d += 2048){
    uint4 zv = *reinterpret_cast<const uint4*>(z + (size_t)b*32768 + d);
    unsigned zw[4] = {zv.x, zv.y, zv.z, zv.w};
    float4 w0 = *reinterpret_cast<const float4*>(Wout + d);
    float4 w1 = *reinterpret_cast<const float4*>(Wout + d + 4);
    s += bfhalf(zw[0],0)*w0.x + bfhalf(zw[0],1)*w0.y + bfhalf(zw[1],0)*w0.z + bfhalf(zw[1],1)*w0.w
       + bfhalf(zw[2],0)*w1.x + bfhalf(zw[2],1)*w1.y + bfhalf(zw[3],0)*w1.z + bfhalf(zw[3],1)*w1.w;
  }
  #pragma unroll
  for (int off = 32; off > 0; off >>= 1) s += __shfl_down(s, off);
  if (l == 0) redp[w] = s;
  __syncthreads();
  if (tid == 0) outp[b] = redp[0] + redp[1] + redp[2] + redp[3] + bout[0];
}

// ---------------- host orchestration ----------------

extern "C" void kernel_launch(void* const* d_in, const int* in_sizes, int n_in,
                              void* d_out, int out_size, void* d_ws, size_t ws_size,
                              hipStream_t stream)
{
  const float* x     = (const float*)d_in[0];
  const float* Wih_x = (const float*)d_in[1];
  const float* Whh_x = (const float*)d_in[2];
  const float* bih_x = (const float*)d_in[3];
  const float* bhh_x = (const float*)d_in[4];
  const float* Wih_z = (const float*)d_in[5];
  const float* Whh_z = (const float*)d_in[6];
  const float* bih_z = (const float*)d_in[7];
  const float* bhh_z = (const float*)d_in[8];
  const float* Wout  = (const float*)d_in[9];
  const float* bout  = (const float*)d_in[10];
  float* outp = (float*)d_out;
  (void)in_sizes; (void)n_in; (void)out_size; (void)ws_size;

  char* basep = (char*)d_ws;
  size_t off = 0;
  auto alloc = [&](size_t bytes)->char*{
    char* r = basep + off; off = (off + bytes + 255) & ~(size_t)255; return r;
  };
  const size_t EL = (size_t)64*128*256;            // 2,097,152 elems per state tensor

  unsigned short* z0b  = (unsigned short*)alloc(EL*2);   // standard z0; ALSO X slot 0 (overwritten at k=6)
  uint4*          z0p  = (uint4*)alloc(EL*2);            // permuted z0 (= hperm of GRU_x)
  uint4*          hpB  = (uint4*)alloc(EL*2);            // hperm scratch for GRU_z evals
  unsigned short* Xb[6]; Xb[0] = z0b;
  for (int s = 1; s < 6; s++) Xb[s] = (unsigned short*)alloc(EL*2);
  unsigned short* Fb[6];
  for (int s = 0; s < 6; s++) Fb[s] = (unsigned short*)alloc(EL*2);
  unsigned short* lowb = (unsigned short*)alloc(EL*2);
  unsigned short* zfin = (unsigned short*)alloc(EL*2);
  unsigned short* xbf  = (unsigned short*)alloc((size_t)64*128*64*2);
  unsigned*       Gi   = (unsigned*)alloc((size_t)64*128*768*4);
  unsigned short* fIx  = (unsigned short*)alloc((size_t)48*2*64*8*2);
  unsigned short* fHx  = (unsigned short*)alloc((size_t)48*8*64*8*2);
  unsigned short* fIz  = (unsigned short*)alloc((size_t)48*8*64*8*2);
  unsigned short* fHz  = (unsigned short*)alloc((size_t)48*8*64*8*2);
  float* biasX  = (float*)alloc(768*4);
  float* biasZ  = (float*)alloc(768*4);
  float* GGT    = (float*)alloc(64*36*4);
  float* alph   = (float*)alloc(64*6*4);
  float* dpart  = (float*)alloc(1024*4);
  float* lowest = (float*)alloc(4);
  int*   stopped= (int*)alloc(4);
  int*   cflag  = (int*)alloc(4);

  P6 XP, FP;
  for (int s = 0; s < 6; s++){ XP.p[s] = Xb[s]; FP.p[s] = Fb[s]; }

  // prep
  bias_comb_k<<<3,256,0,stream>>>(bih_x, bhh_x, biasX);
  bias_comb_k<<<3,256,0,stream>>>(bih_z, bhh_z, biasZ);
  cvt_bf16_k<<<2048,256,0,stream>>>(x, xbf, 64*128*64);
  prep_bfrag_k<<<24,256,0,stream>>>(Wih_x, fIx, 2);
  prep_bfrag_k<<<96,256,0,stream>>>(Whh_x, fHx, 8);
  prep_bfrag_k<<<96,256,0,stream>>>(Wih_z, fIz, 8);
  prep_bfrag_k<<<96,256,0,stream>>>(Whh_z, fHz, 8);
  init_sc_k<<<1,1,0,stream>>>(lowest, stopped, cflag);

  dim3 gg(128, 8);
  // z0 = GRU_x(x); X0 = z0 (z0b); z0p = hperm directly
  gemm_k<<<gg,256,0,stream>>>(xbf, fIx, biasX, Gi, 2);
  recurrent_k<<<4,512,0,stream>>>(Gi, fHx, bhh_x, z0p);
  act0_k<<<1024,256,0,stream>>>(z0p, z0b);
  hipMemcpyAsync(lowb, z0b, EL*2, hipMemcpyDeviceToDevice, stream);   // lowest_xest init = x0
  // F0 = f(x0)
  gemm_k<<<gg,256,0,stream>>>(z0b, fIz, biasZ, Gi, 8);
  recurrent_k<<<4,512,0,stream>>>(Gi, fHz, bhh_z, hpB);
  act1_k<<<1024,256,0,stream>>>(hpB, z0p, Fb[0], nullptr, nullptr);
  hipMemcpyAsync(Xb[1], Fb[0], EL*2, hipMemcpyDeviceToDevice, stream); // X1 = F0
  // F1 = f(F0)
  gemm_k<<<gg,256,0,stream>>>(Fb[0], fIz, biasZ, Gi, 8);
  recurrent_k<<<4,512,0,stream>>>(Gi, fHz, bhh_z, hpB);
  act1_k<<<1024,256,0,stream>>>(hpB, z0p, Fb[1], nullptr, nullptr);

  for (int k = 2; k < 50; k++){
    int s = k % 6;
    int n = (k < 6) ? k : 6;
    anderson_pre_k<<<64,256,0,stream>>>(XP, FP, GGT);
    anderson_solve_k<<<1,64,0,stream>>>(GGT, alph, n);
    xnew_k<<<1024,256,0,stream>>>(FP, alph, Xb[s]);
    gemm_k<<<gg,256,0,stream>>>(Xb[s], fIz, biasZ, Gi, 8);
    recurrent_k<<<4,512,0,stream>>>(Gi, fHz, bhh_z, hpB);
    act1_k<<<1024,256,0,stream>>>(hpB, z0p, Fb[s], Xb[s], dpart);
    anderson_post_k<<<1,256,0,stream>>>(dpart, lowest, stopped, cflag);
    cond_copy_k<<<1024,256,0,stream>>>((const uint4*)Xb[s], (uint4*)lowb, cflag);
  }

  // final differentiable step + output projection
  gemm_k<<<gg,256,0,stream>>>(lowb, fIz, biasZ, Gi, 8);
  recurrent_k<<<4,512,0,stream>>>(Gi, fHz, bhh_z, hpB);
  act1_k<<<1024,256,0,stream>>>(hpB, z0p, zfin, nullptr, nullptr);
  outproj_k<<<64,256,0,stream>>>(zfin, Wout, bout, outp);
}

// Round 5
// 13208.865 us; speedup vs baseline: 2.7045x; 1.1560x over previous
//
#include <hip/hip_runtime.h>
#include <hip/hip_bf16.h>

// DEQ-GRU on MI355X. R5: (1) recurrence over 8 WGs x 8 batch rows (M=16 tiles half-padded,
// C-fragments redistributed across all 64 lanes via shfl so gate VALU per CU halves),
// (2) anderson pre+solve fused, diff taken from GGT diagonal one iteration later,
// (3) act1 dual-write kills the X1=F0 memcpy.

#define DEVFN __device__ __forceinline__

typedef __attribute__((ext_vector_type(8))) short bf16x8_t;
typedef __attribute__((ext_vector_type(4))) float f32x4_t;

DEVFN unsigned short f2bf(float f){
  union { float f; unsigned u; } v; v.f = f;
  unsigned r = v.u + 0x7fffu + ((v.u >> 16) & 1u);
  return (unsigned short)(r >> 16);
}
DEVFN float bf2f(unsigned short h){
  union { unsigned u; float f; } v; v.u = ((unsigned)h) << 16; return v.f;
}
DEVFN float bfhalf(unsigned dw, int hi){
  union { unsigned u; float f; } v; v.u = hi ? (dw & 0xffff0000u) : (dw << 16); return v.f;
}
DEVFN float fexp2f_(float x){ return __builtin_amdgcn_exp2f(x); }
DEVFN float frcp_(float x){ return __builtin_amdgcn_rcpf(x); }
DEVFN float sigm(float x){ return frcp_(1.f + fexp2f_(-1.4426950408889634f * x)); }
DEVFN float tanh_fast(float x){ return 1.f - 2.f * frcp_(1.f + fexp2f_(2.8853900817779268f * x)); }

struct P6 { const unsigned short* p[6]; };

// ---------------- prep kernels ----------------

__global__ void bias_comb_k(const float* __restrict__ bih, const float* __restrict__ bhh,
                            float* __restrict__ outb){
  int i = blockIdx.x*256 + threadIdx.x;
  if (i < 768) outb[i] = bih[i] + (i < 512 ? bhh[i] : 0.f);
}

__global__ void cvt_bf16_k(const float* __restrict__ in, unsigned short* __restrict__ outp, int nel){
  int i = blockIdx.x*256 + threadIdx.x;
  if (i < nel) outp[i] = f2bf(in[i]);
}

// W [768][K] fp32 -> B-fragment-ordered bf16
__global__ void prep_bfrag_k(const float* __restrict__ W, unsigned short* __restrict__ outp, int KT){
  int idx = blockIdx.x*256 + threadIdx.x;
  int total = 48*KT*64;
  if (idx >= total) return;
  int lane = idx & 63;
  int ktn = idx >> 6;
  int kt = ktn % KT, nt = ktn / KT;
  int K = KT*32;
  int n  = nt*16 + (lane & 15);
  int k0 = kt*32 + (lane >> 4)*8;
  unsigned ow[4];
  #pragma unroll
  for (int i2 = 0; i2 < 4; i2++){
    unsigned lo = f2bf(W[(size_t)n*K + k0 + 2*i2]);
    unsigned hi = f2bf(W[(size_t)n*K + k0 + 2*i2 + 1]);
    ow[i2] = lo | (hi << 16);
  }
  uint4 st; st.x = ow[0]; st.y = ow[1]; st.z = ow[2]; st.w = ow[3];
  *reinterpret_cast<uint4*>(outp + (size_t)idx*8) = st;
}

__global__ void init_sc_k(float* lowest, int* stopped, int* cflag){
  *lowest = 1e8f; *stopped = 0; *cflag = 0;
}

// ---------------- input-projection GEMM ----------------
__launch_bounds__(256, 4)
__global__ void gemm_k(const unsigned short* __restrict__ A,
                       const unsigned short* __restrict__ Bf,
                       const float* __restrict__ bias,
                       unsigned* __restrict__ Gi,
                       int KT)
{
  const int K = KT*32;
  const int mb = blockIdx.x;        // 0..127, 64 rows each
  const int nb = blockIdx.y;        // 0..7, 96 cols each
  const int tid = threadIdx.x, l = tid & 63, w = tid >> 6;
  const int l15 = l & 15, l4 = l >> 4;
  __shared__ unsigned short As[64*256];

  const int cpr = K >> 3;
  for (int c = tid; c < 64*cpr; c += 256){
    int row = c / cpr, ch = c % cpr;
    uint4 v = *reinterpret_cast<const uint4*>(A + ((size_t)(mb*64 + row))*K + ch*8);
    int pch = ch ^ (row & 7);
    *reinterpret_cast<uint4*>(&As[row*K + pch*8]) = v;
  }
  __syncthreads();

  f32x4_t acc[6];
  #pragma unroll
  for (int j = 0; j < 6; j++){
    float bv = bias[nb*96 + j*16 + l15];
    acc[j] = (f32x4_t){bv, bv, bv, bv};
  }
  const int arow = 16*w + l15;
  for (int kt = 0; kt < KT; kt++){
    int ch = (kt*4 + l4) ^ (arow & 7);
    bf16x8_t af = *reinterpret_cast<const bf16x8_t*>(&As[arow*K + ch*8]);
    #pragma unroll
    for (int j = 0; j < 6; j++){
      bf16x8_t bb = *reinterpret_cast<const bf16x8_t*>(Bf + (((size_t)((nb*6 + j)*KT + kt))*64 + l)*8);
      acc[j] = __builtin_amdgcn_mfma_f32_16x16x32_bf16(af, bb, acc[j], 0, 0, 0);
    }
  }
  // epilogue -> permuted Gi (layout unchanged from R3/R4)
  const int bidx = mb >> 1;
  const int grp = bidx >> 4, rq = bidx & 3, lq = ((bidx >> 2) & 3)*16 + l15;
  #pragma unroll
  for (int p = 0; p < 3; p++){
    int nb32 = 3*nb + p;
    int wq = nb32 & 7, gate = nb32 >> 3;
    #pragma unroll
    for (int r = 0; r < 4; r++){
      int t = (mb & 1)*64 + 16*w + 4*l4 + r;
      unsigned lo = f2bf(acc[2*p][r]);
      unsigned hi = f2bf(acc[2*p + 1][r]);
      size_t di = ((((size_t)(grp*128 + t)*8 + wq)*3 + gate)*4 + rq)*64 + lq;
      Gi[di] = lo | (hi << 16);
    }
  }
}

// ---------------- sequential GRU recurrence (8 WGs x 8 batch rows) ----------------
// WG g owns b in [8g, 8g+8). M=16 A-tile rows 8..15 are zero-padded (never written).
// After MFMA, odd accumulators (tt=1 columns) are shuffled from lane l-32 so that
// every lane computes 4 gate elements: lane tt = l>>5, lh4 = (l>>4)&1, rows b=8g+4*lh4+r.
__launch_bounds__(512, 2)
__global__ void recurrent_k(const unsigned* __restrict__ Gi,
                            const unsigned short* __restrict__ Wfrag,
                            const float* __restrict__ bhh,
                            uint2* __restrict__ hperm)
{
  const int g = blockIdx.x;                      // 0..7
  const int tid = threadIdx.x;
  const int l = tid & 63, w = tid >> 6;
  const int l15 = l & 15;
  const int tt = l >> 5;                         // 0/1: which 16-col half this lane finishes
  const int lh4 = (l >> 4) & 1;                  // row group within the 8 real rows

  __shared__ unsigned short hbuf[2][4096];       // 2 x 8KB A-fragment-ordered h (bf16)
  __shared__ unsigned short wlds[8*6*64*8];      // 48KB: kt=7 frags, nt 0..5 per wave

  const int ntl[6] = {2*w, 2*w + 1, 16 + 2*w, 17 + 2*w, 32 + 2*w, 33 + 2*w};

  bf16x8_t wf[6][7];
  #pragma unroll
  for (int i = 0; i < 6; i++)
    #pragma unroll
    for (int kt = 0; kt < 7; kt++)
      wf[i][kt] = *reinterpret_cast<const bf16x8_t*>(Wfrag + (((size_t)(ntl[i]*8 + kt))*64 + l)*8);
  #pragma unroll
  for (int i = 0; i < 6; i++){
    bf16x8_t v = *reinterpret_cast<const bf16x8_t*>(Wfrag + (((size_t)(ntl[i]*8 + 7))*64 + l)*8);
    *reinterpret_cast<bf16x8_t*>(&wlds[((w*6 + i)*64 + l)*8]) = v;
  }

  const float bn0 = bhh[ntl[4]*16 + l15];        // n-gate recurrent bias, tt=0 cols
  const float bn1 = bhh[ntl[5]*16 + l15];        // tt=1 cols

  { uint4 z = {0,0,0,0};
    *reinterpret_cast<uint4*>(&hbuf[0][tid*8]) = z;
    *reinterpret_cast<uint4*>(&hbuf[1][tid*8]) = z; }
  float hold[4];
  #pragma unroll
  for (int r = 0; r < 4; r++) hold[r] = 0.f;

  // Gi addressing (gemm epilogue layout): b = 8g + 4*lh4 + r
  const int grp = g >> 1;
  const int lq  = ((2*g + lh4) & 3)*16 + l15;

  int pb = 0;
  __syncthreads();

  for (int t = 0; t < 128; t++){
    // prefetch gate inputs (independent of hbuf)
    const size_t gib = ((size_t)(grp*128 + t)*8 + w)*768 + lq;
    unsigned gd[3][4];
    #pragma unroll
    for (int gate = 0; gate < 3; gate++)
      #pragma unroll
      for (int r = 0; r < 4; r++)
        gd[gate][r] = Gi[gib + (size_t)gate*256 + r*64];

    f32x4_t acc[6];
    #pragma unroll
    for (int i = 0; i < 4; i++) acc[i] = (f32x4_t){0.f, 0.f, 0.f, 0.f};
    acc[4] = (f32x4_t){bn0, bn0, bn0, bn0};
    acc[5] = (f32x4_t){bn1, bn1, bn1, bn1};

    #pragma unroll
    for (int kt = 0; kt < 8; kt++){
      bf16x8_t af = *reinterpret_cast<const bf16x8_t*>(&hbuf[pb][(kt*64 + l)*8]);
      if (kt < 7){
        #pragma unroll
        for (int i = 0; i < 6; i++)
          acc[i] = __builtin_amdgcn_mfma_f32_16x16x32_bf16(af, wf[i][kt], acc[i], 0, 0, 0);
      } else {
        #pragma unroll
        for (int i = 0; i < 6; i++){
          bf16x8_t bb = *reinterpret_cast<const bf16x8_t*>(&wlds[((w*6 + i)*64 + l)*8]);
          acc[i] = __builtin_amdgcn_mfma_f32_16x16x32_bf16(af, bb, acc[i], 0, 0, 0);
        }
      }
    }

    // redistribute: lanes >=32 take the odd (tt=1) accumulators from lane l-32
    float ga[3][4];
    #pragma unroll
    for (int p = 0; p < 3; p++)
      #pragma unroll
      for (int r = 0; r < 4; r++){
        float hi = __shfl(acc[2*p + 1][r], l & 31);
        ga[p][r] = (tt == 0) ? acc[2*p][r] : hi;
      }

    unsigned short hb[4];
    #pragma unroll
    for (int r = 0; r < 4; r++){
      float rg = sigm(bfhalf(gd[0][r], tt) + ga[0][r]);
      float zg = sigm(bfhalf(gd[1][r], tt) + ga[1][r]);
      float nn = tanh_fast(bfhalf(gd[2][r], tt) + rg*ga[2][r]);
      float h = nn + zg*(hold[r] - nn);
      hold[r] = h;
      unsigned short hbv = f2bf(h);
      hb[r] = hbv;
      // A-frag slot: row = 4*lh4 + r (real rows 0..7), col j = 32w + 16tt + l15
      int lp = (4*lh4 + r) + 32*tt + 16*(l15 >> 3);
      hbuf[pb ^ 1][(w*64 + lp)*8 + (l15 & 7)] = hbv;
    }
    // coalesced 8B store of this lane's 4 h values
    uint2 hp;
    hp.x = (unsigned)hb[0] | ((unsigned)hb[1] << 16);
    hp.y = (unsigned)hb[2] | ((unsigned)hb[3] << 16);
    hperm[((size_t)(g*128 + t))*512 + (size_t)w*64 + l] = hp;

    // raw barrier: drain LDS only; global ops stay in flight
    __builtin_amdgcn_sched_barrier(0);
    asm volatile("s_waitcnt lgkmcnt(0)" ::: "memory");
    __builtin_amdgcn_s_barrier();
    __builtin_amdgcn_sched_barrier(0);
    pb ^= 1;
  }
}

// ---------------- activation kernels (fully parallel, uint2 hperm layout) ----------------
// idx = ((gp*128 + t)*8 + w)*64 + l ; lane holds 4 elems: b = 8gp+4*lh4+r, j = 32w+16tt+l15

__global__ void act0_k(const uint2* __restrict__ hperm, unsigned short* __restrict__ outstd){
  int idx = blockIdx.x*256 + threadIdx.x;        // 524288
  int l = idx & 63, w = (idx >> 6) & 7, t = (idx >> 9) & 127, gp = idx >> 16;
  int tt = l >> 5, lh4 = (l >> 4) & 1, l15 = l & 15;
  uint2 hp = hperm[idx];
  #pragma unroll
  for (int r = 0; r < 4; r++){
    unsigned dw = (r < 2) ? hp.x : hp.y;
    unsigned short v = (r & 1) ? (unsigned short)(dw >> 16) : (unsigned short)(dw & 0xffff);
    int b = 8*gp + 4*lh4 + r;
    int j = 32*w + 16*tt + l15;
    outstd[((size_t)b*128 + t)*256 + j] = v;
  }
}

__global__ void act1_k(const uint2* __restrict__ hperm, const uint2* __restrict__ z0p,
                       unsigned short* __restrict__ Fout, unsigned short* __restrict__ Fout2){
  int idx = blockIdx.x*256 + threadIdx.x;        // 524288
  int l = idx & 63, w = (idx >> 6) & 7, t = (idx >> 9) & 127, gp = idx >> 16;
  int tt = l >> 5, lh4 = (l >> 4) & 1, l15 = l & 15;
  uint2 hp = hperm[idx];
  uint2 zp = z0p[idx];
  #pragma unroll
  for (int r = 0; r < 4; r++){
    float h  = bfhalf((r < 2) ? hp.x : hp.y, r & 1);
    float z0 = bfhalf((r < 2) ? zp.x : zp.y, r & 1);
    float ov = tanh_fast(h + z0);
    int b = 8*gp + 4*lh4 + r;
    int j = 32*w + 16*tt + l15;
    size_t o = ((size_t)b*128 + t)*256 + j;
    unsigned short ob = f2bf(ov);
    Fout[o] = ob;
    if (Fout2) Fout2[o] = ob;
  }
}

// ---------------- Anderson: fused Gram + bordered solve ----------------

DEVFN int symq(int i, int j){
  int a = i < j ? i : j, b2 = i < j ? j : i;
  return a*6 - (a*(a-1))/2 + (b2 - a);
}

__launch_bounds__(512, 2)
__global__ void pre_solve_k(P6 X, P6 F, float* __restrict__ GGT,
                            float* __restrict__ alpha, int n)
{
  const int b = blockIdx.x, tid = threadIdx.x;
  const int l = tid & 63, w = tid >> 6;
  __shared__ float redp[8*21];
  __shared__ float ggts[21];
  const size_t base = (size_t)b*32768;
  float p[21];
  #pragma unroll
  for (int q = 0; q < 21; q++) p[q] = 0.f;
  for (int d0 = tid*8; d0 < 32768; d0 += 4096){
    float gv[6][8];
    #pragma unroll
    for (int s = 0; s < 6; s++){
      uint4 fv = *reinterpret_cast<const uint4*>(F.p[s] + base + d0);
      uint4 xv = *reinterpret_cast<const uint4*>(X.p[s] + base + d0);
      unsigned fw[4] = {fv.x, fv.y, fv.z, fv.w};
      unsigned xw[4] = {xv.x, xv.y, xv.z, xv.w};
      #pragma unroll
      for (int e = 0; e < 8; e++) gv[s][e] = bfhalf(fw[e >> 1], e & 1) - bfhalf(xw[e >> 1], e & 1);
    }
    int q = 0;
    #pragma unroll
    for (int i = 0; i < 6; i++)
      #pragma unroll
      for (int jj = i; jj < 6; jj++){
        float s2 = 0.f;
        #pragma unroll
        for (int e = 0; e < 8; e++) s2 += gv[i][e]*gv[jj][e];
        p[q++] += s2;
      }
  }
  #pragma unroll
  for (int q = 0; q < 21; q++){
    float v = p[q];
    #pragma unroll
    for (int off = 32; off > 0; off >>= 1) v += __shfl_down(v, off);
    if (l == 0) redp[w*21 + q] = v;
  }
  __syncthreads();
  if (tid < 21){
    float s = 0.f;
    #pragma unroll
    for (int i = 0; i < 8; i++) s += redp[i*21 + tid];
    ggts[tid] = s;
  }
  __syncthreads();
  if (tid == 0){
    // write raw Gram (diag used by post2_k)
    const int PI[21] = {0,0,0,0,0,0, 1,1,1,1,1, 2,2,2,2, 3,3,3, 4,4, 5};
    const int PJ[21] = {0,1,2,3,4,5, 1,2,3,4,5, 2,3,4,5, 3,4,5, 4,5, 5};
    for (int q = 0; q < 21; q++){
      GGT[b*36 + PI[q]*6 + PJ[q]] = ggts[q];
      GGT[b*36 + PJ[q]*6 + PI[q]] = ggts[q];
    }
    // bordered 7x7 solve
    int m = n + 1;
    float A[7][8];
    for (int i = 0; i < 7; i++)
      for (int j = 0; j < 8; j++) A[i][j] = 0.f;
    for (int j = 1; j < m; j++) A[0][j] = 1.f;
    for (int i = 1; i < m; i++){
      A[i][0] = 1.f;
      for (int j = 1; j < m; j++)
        A[i][j] = ggts[symq(i-1, j-1)] + ((i == j) ? 1e-4f : 0.f);
    }
    A[0][7] = 1.f;
    for (int c = 0; c < m; c++){
      int piv = c; float mx = fabsf(A[c][c]);
      for (int i = c + 1; i < m; i++){
        float v = fabsf(A[i][c]);
        if (v > mx){ mx = v; piv = i; }
      }
      if (piv != c)
        for (int j = 0; j < 8; j++){ float tsw = A[c][j]; A[c][j] = A[piv][j]; A[piv][j] = tsw; }
      float inv = 1.f / A[c][c];
      for (int j = c; j < 8; j++) A[c][j] *= inv;
      for (int i = 0; i < m; i++) if (i != c){
        float f = A[i][c];
        for (int j = c; j < 8; j++) A[i][j] -= f*A[c][j];
      }
    }
    for (int s = 0; s < 6; s++) alpha[b*6 + s] = (s + 1 < m) ? A[s+1][7] : 0.f;
  }
}

// diff_k = sqrt( sum_b GGT_b[s][s] ) ; update lowest/stopped/cflag
__global__ void post2_k(const float* __restrict__ GGT, int s,
                        float* lowest, int* stopped, int* cflag){
  int l = threadIdx.x;                           // 64
  float v = GGT[l*36 + s*7];
  #pragma unroll
  for (int off = 32; off > 0; off >>= 1) v += __shfl_down(v, off);
  if (l == 0){
    float d = sqrtf(v);
    int act = (*stopped == 0);
    int imp = act && (d < *lowest);
    *cflag = imp;
    if (imp) *lowest = d;
    if (act && (d < 1e-3f)) *stopped = 1;
  }
}

__global__ void xnew_k(P6 F, const float* __restrict__ al, unsigned short* __restrict__ Xd)
{
  size_t idx = (size_t)blockIdx.x*256 + threadIdx.x;   // 262144
  size_t e0 = idx*8;
  int b = (int)(e0 >> 15);
  float a[6];
  #pragma unroll
  for (int s = 0; s < 6; s++) a[s] = al[b*6 + s];
  float o[8];
  #pragma unroll
  for (int e = 0; e < 8; e++) o[e] = 0.f;
  #pragma unroll
  for (int s = 0; s < 6; s++){
    uint4 fv = *reinterpret_cast<const uint4*>(F.p[s] + e0);
    unsigned fw[4] = {fv.x, fv.y, fv.z, fv.w};
    #pragma unroll
    for (int e = 0; e < 8; e++) o[e] += a[s]*bfhalf(fw[e >> 1], e & 1);
  }
  unsigned ow[4];
  #pragma unroll
  for (int i2 = 0; i2 < 4; i2++){
    unsigned lo = f2bf(o[2*i2]), hi = f2bf(o[2*i2 + 1]);
    ow[i2] = lo | (hi << 16);
  }
  uint4 st; st.x = ow[0]; st.y = ow[1]; st.z = ow[2]; st.w = ow[3];
  *reinterpret_cast<uint4*>(Xd + e0) = st;
}

__global__ void cond_copy_k(const uint4* __restrict__ s, uint4* __restrict__ d, const int* __restrict__ flag){
  if (*flag == 0) return;
  size_t i = (size_t)blockIdx.x*256 + threadIdx.x;
  d[i] = s[i];
}

__global__ void outproj_k(const unsigned short* __restrict__ z, const float* __restrict__ Wout,
                          const float* __restrict__ bout, float* __restrict__ outp){
  const int b = blockIdx.x, tid = threadIdx.x, l = tid & 63, w = tid >> 6;
  __shared__ float redp[4];
  float s = 0.f;
  for (int d = tid*8; d < 32768; d += 2048){
    uint4 zv = *reinterpret_cast<const uint4*>(z + (size_t)b*32768 + d);
    unsigned zw[4] = {zv.x, zv.y, zv.z, zv.w};
    float4 w0 = *reinterpret_cast<const float4*>(Wout + d);
    float4 w1 = *reinterpret_cast<const float4*>(Wout + d + 4);
    s += bfhalf(zw[0],0)*w0.x + bfhalf(zw[0],1)*w0.y + bfhalf(zw[1],0)*w0.z + bfhalf(zw[1],1)*w0.w
       + bfhalf(zw[2],0)*w1.x + bfhalf(zw[2],1)*w1.y + bfhalf(zw[3],0)*w1.z + bfhalf(zw[3],1)*w1.w;
  }
  #pragma unroll
  for (int off = 32; off > 0; off >>= 1) s += __shfl_down(s, off);
  if (l == 0) redp[w] = s;
  __syncthreads();
  if (tid == 0) outp[b] = redp[0] + redp[1] + redp[2] + redp[3] + bout[0];
}

// ---------------- host orchestration ----------------

extern "C" void kernel_launch(void* const* d_in, const int* in_sizes, int n_in,
                              void* d_out, int out_size, void* d_ws, size_t ws_size,
                              hipStream_t stream)
{
  const float* x     = (const float*)d_in[0];
  const float* Wih_x = (const float*)d_in[1];
  const float* Whh_x = (const float*)d_in[2];
  const float* bih_x = (const float*)d_in[3];
  const float* bhh_x = (const float*)d_in[4];
  const float* Wih_z = (const float*)d_in[5];
  const float* Whh_z = (const float*)d_in[6];
  const float* bih_z = (const float*)d_in[7];
  const float* bhh_z = (const float*)d_in[8];
  const float* Wout  = (const float*)d_in[9];
  const float* bout  = (const float*)d_in[10];
  float* outp = (float*)d_out;
  (void)in_sizes; (void)n_in; (void)out_size; (void)ws_size;

  char* basep = (char*)d_ws;
  size_t off = 0;
  auto alloc = [&](size_t bytes)->char*{
    char* r = basep + off; off = (off + bytes + 255) & ~(size_t)255; return r;
  };
  const size_t EL = (size_t)64*128*256;            // elems per state tensor

  unsigned short* z0b  = (unsigned short*)alloc(EL*2);   // standard z0; X slot 0
  uint2*          z0p  = (uint2*)alloc(EL*2);            // permuted z0 (= hperm of GRU_x)
  uint2*          hpB  = (uint2*)alloc(EL*2);            // hperm scratch for GRU_z evals
  unsigned short* Xb[6]; Xb[0] = z0b;
  for (int s = 1; s < 6; s++) Xb[s] = (unsigned short*)alloc(EL*2);
  unsigned short* Fb[6];
  for (int s = 0; s < 6; s++) Fb[s] = (unsigned short*)alloc(EL*2);
  unsigned short* lowb = (unsigned short*)alloc(EL*2);
  unsigned short* zfin = (unsigned short*)alloc(EL*2);
  unsigned short* xbf  = (unsigned short*)alloc((size_t)64*128*64*2);
  unsigned*       Gi   = (unsigned*)alloc((size_t)64*128*768*4);
  unsigned short* fIx  = (unsigned short*)alloc((size_t)48*2*64*8*2);
  unsigned short* fHx  = (unsigned short*)alloc((size_t)48*8*64*8*2);
  unsigned short* fIz  = (unsigned short*)alloc((size_t)48*8*64*8*2);
  unsigned short* fHz  = (unsigned short*)alloc((size_t)48*8*64*8*2);
  float* biasX  = (float*)alloc(768*4);
  float* biasZ  = (float*)alloc(768*4);
  float* GGT    = (float*)alloc(64*36*4);
  float* alph   = (float*)alloc(64*6*4);
  float* lowest = (float*)alloc(4);
  int*   stopped= (int*)alloc(4);
  int*   cflag  = (int*)alloc(4);

  P6 XP, FP;
  for (int s = 0; s < 6; s++){ XP.p[s] = Xb[s]; FP.p[s] = Fb[s]; }

  // prep
  bias_comb_k<<<3,256,0,stream>>>(bih_x, bhh_x, biasX);
  bias_comb_k<<<3,256,0,stream>>>(bih_z, bhh_z, biasZ);
  cvt_bf16_k<<<2048,256,0,stream>>>(x, xbf, 64*128*64);
  prep_bfrag_k<<<24,256,0,stream>>>(Wih_x, fIx, 2);
  prep_bfrag_k<<<96,256,0,stream>>>(Whh_x, fHx, 8);
  prep_bfrag_k<<<96,256,0,stream>>>(Wih_z, fIz, 8);
  prep_bfrag_k<<<96,256,0,stream>>>(Whh_z, fHz, 8);
  init_sc_k<<<1,1,0,stream>>>(lowest, stopped, cflag);

  dim3 gg(128, 8);
  // z0 = GRU_x(x); X0 = z0
  gemm_k<<<gg,256,0,stream>>>(xbf, fIx, biasX, Gi, 2);
  recurrent_k<<<8,512,0,stream>>>(Gi, fHx, bhh_x, z0p);
  act0_k<<<2048,256,0,stream>>>(z0p, z0b);
  hipMemcpyAsync(lowb, z0b, EL*2, hipMemcpyDeviceToDevice, stream);   // lowest_xest init = x0
  // F0 = f(x0); X1 = F0
  gemm_k<<<gg,256,0,stream>>>(z0b, fIz, biasZ, Gi, 8);
  recurrent_k<<<8,512,0,stream>>>(Gi, fHz, bhh_z, hpB);
  act1_k<<<2048,256,0,stream>>>(hpB, z0p, Fb[0], Xb[1]);
  // F1 = f(F0)
  gemm_k<<<gg,256,0,stream>>>(Fb[0], fIz, biasZ, Gi, 8);
  recurrent_k<<<8,512,0,stream>>>(Gi, fHz, bhh_z, hpB);
  act1_k<<<2048,256,0,stream>>>(hpB, z0p, Fb[1], nullptr);

  for (int k = 2; k < 50; k++){
    int s = k % 6;
    int n = (k < 6) ? k : 6;
    pre_solve_k<<<64,512,0,stream>>>(XP, FP, GGT, alph, n);
    if (k > 2){
      int sp = (k - 1) % 6;                      // previous iteration's diff from Gram diag
      post2_k<<<1,64,0,stream>>>(GGT, sp, lowest, stopped, cflag);
      cond_copy_k<<<1024,256,0,stream>>>((const uint4*)Xb[sp], (uint4*)lowb, cflag);
    }
    xnew_k<<<1024,256,0,stream>>>(FP, alph, Xb[s]);
    gemm_k<<<gg,256,0,stream>>>(Xb[s], fIz, biasZ, Gi, 8);
    recurrent_k<<<8,512,0,stream>>>(Gi, fHz, bhh_z, hpB);
    act1_k<<<2048,256,0,stream>>>(hpB, z0p, Fb[s], nullptr);
  }
  // last iteration's diff (k=49, slot 1)
  pre_solve_k<<<64,512,0,stream>>>(XP, FP, GGT, alph, 6);
  post2_k<<<1,64,0,stream>>>(GGT, 49 % 6, lowest, stopped, cflag);
  cond_copy_k<<<1024,256,0,stream>>>((const uint4*)Xb[49 % 6], (uint4*)lowb, cflag);

  // final differentiable step + output projection
  gemm_k<<<gg,256,0,stream>>>(lowb, fIz, biasZ, Gi, 8);
  recurrent_k<<<8,512,0,stream>>>(Gi, fHz, bhh_z, hpB);
  act1_k<<<2048,256,0,stream>>>(hpB, z0p, zfin, nullptr);
  outproj_k<<<64,256,0,stream>>>(zfin, Wout, bout, outp);
}